// Round 1
// baseline (3683.182 us; speedup 1.0000x reference)
//
#include <hip/hip_runtime.h>
#include <math.h>

#define NTOK   32768
#define DIMS   128
#define QST    8
#define KC     1024

#define SZ_QUANT (NTOK*DIMS)
#define SZ_CODES (NTOK*QST)
#define SZ_W     (QST*KC*DIMS)
#define OFF_CODES (SZ_QUANT)
#define OFF_LOSS  (OFF_CODES + SZ_CODES)
#define OFF_W     (OFF_LOSS + 1)
#define OFF_RM    (OFF_W + SZ_W)
#define OFF_CC    (OFF_RM + SZ_W)

// LDS A tile: [d][tok] transposed, row stride 64 floats; XOR quad-swizzle so both
// the coalesced staging writes and the per-d float4 reads stay <=4-way conflicted.
__device__ __forceinline__ int a_idx(int d, int tok) {
    int qs = ((tok >> 2) ^ (d >> 2)) & 15;
    return d * 64 + (qs << 2) + (tok & 3);
}

__global__ __launch_bounds__(256, 2)
void rvq_stage(const float* __restrict__ rin,
               float* __restrict__ rout,
               const float* __restrict__ wst,     // weight of this stage [K][D]
               const float* __restrict__ wsqst,   // ||w||^2 of this stage [K]
               float* __restrict__ codes_out,     // [N][Q] float
               float* __restrict__ rm_acc,        // this stage's running-mean accumulator [K][D]
               float* __restrict__ cc_acc,        // this stage's count accumulator [K]
               int stage)
{
    __shared__ float A[DIMS * 64];     // 32 KiB: r tile, [d][tok] swizzled
    __shared__ float Bt[32 * 256];     // 32 KiB: w chunk, [d_local][code] swizzled
    __shared__ float red_d[64 * 16];
    __shared__ int   red_k[64 * 16];
    __shared__ int   kbest[64];

    const int t    = threadIdx.x;
    const int tx   = t & 15;    // token group: tokens 4*tx .. 4*tx+3
    const int ty   = t >> 4;    // code group: 16 codes per thread
    const int tok0 = blockIdx.x * 64;

    // ---- stage A: 64 tokens x 128 dims (coalesced read, transposed swizzled write)
    #pragma unroll
    for (int q = 0; q < 8; ++q) {
        int idx = q * 256 + t;          // 2048 float4s
        int tok = idx >> 5;
        int dq  = idx & 31;             // d-quad (d = 4*dq..4*dq+3)
        float4 v = *reinterpret_cast<const float4*>(rin + (size_t)(tok0 + tok) * DIMS + dq * 4);
        int qs   = ((tok >> 2) ^ dq) & 15;
        int base = (qs << 2) + (tok & 3);
        A[(dq * 4 + 0) * 64 + base] = v.x;
        A[(dq * 4 + 1) * 64 + base] = v.y;
        A[(dq * 4 + 2) * 64 + base] = v.z;
        A[(dq * 4 + 3) * 64 + base] = v.w;
    }

    float best[4];
    int   bkst[4];
    #pragma unroll
    for (int i = 0; i < 4; ++i) { best[i] = INFINITY; bkst[i] = 0; }

    for (int ct = 0; ct < 4; ++ct) {          // 4 code tiles of 256
        const int cbase = ct * 256;
        float acc[4][16];
        #pragma unroll
        for (int i = 0; i < 4; ++i)
            #pragma unroll
            for (int j = 0; j < 16; ++j) acc[i][j] = 0.0f;

        for (int dc = 0; dc < 4; ++dc) {      // 4 chunks of 32 dims
            __syncthreads();
            // stage B chunk: 256 codes x 32 dims, transposed+swizzled
            #pragma unroll
            for (int q = 0; q < 8; ++q) {
                int idx = q * 256 + t;        // 2048 float4s
                int c   = idx >> 3;           // code 0..255
                int dq  = idx & 7;            // d-quad within chunk
                float4 v = *reinterpret_cast<const float4*>(
                    wst + (size_t)(cbase + c) * DIMS + dc * 32 + dq * 4);
                int qs   = ((c >> 2) ^ dq) & 63;
                int base = (qs << 2) + (c & 3);
                Bt[(dq * 4 + 0) * 256 + base] = v.x;
                Bt[(dq * 4 + 1) * 256 + base] = v.y;
                Bt[(dq * 4 + 2) * 256 + base] = v.z;
                Bt[(dq * 4 + 3) * 256 + base] = v.w;
            }
            __syncthreads();

            #pragma unroll
            for (int dq = 0; dq < 8; ++dq) {
                const float* Ap  = &A[(dc * 32 + dq * 4) * 64 + ((tx ^ ((dc * 8 + dq) & 15)) << 2)];
                const float* Bp0 = &Bt[(dq * 4) * 256 + ((((4 * ty + 0) ^ dq) & 63) << 2)];
                const float* Bp1 = &Bt[(dq * 4) * 256 + ((((4 * ty + 1) ^ dq) & 63) << 2)];
                const float* Bp2 = &Bt[(dq * 4) * 256 + ((((4 * ty + 2) ^ dq) & 63) << 2)];
                const float* Bp3 = &Bt[(dq * 4) * 256 + ((((4 * ty + 3) ^ dq) & 63) << 2)];
                #pragma unroll
                for (int dd = 0; dd < 4; ++dd) {
                    float4 av = *reinterpret_cast<const float4*>(Ap  + dd * 64);
                    float4 b0 = *reinterpret_cast<const float4*>(Bp0 + dd * 256);
                    float4 b1 = *reinterpret_cast<const float4*>(Bp1 + dd * 256);
                    float4 b2 = *reinterpret_cast<const float4*>(Bp2 + dd * 256);
                    float4 b3 = *reinterpret_cast<const float4*>(Bp3 + dd * 256);
                    const float a[4]  = {av.x, av.y, av.z, av.w};
                    const float bb[16] = {b0.x,b0.y,b0.z,b0.w, b1.x,b1.y,b1.z,b1.w,
                                          b2.x,b2.y,b2.z,b2.w, b3.x,b3.y,b3.z,b3.w};
                    #pragma unroll
                    for (int i = 0; i < 4; ++i)
                        #pragma unroll
                        for (int j = 0; j < 16; ++j)
                            acc[i][j] = fmaf(a[i], bb[j], acc[i][j]);
                }
            }
        }

        // dist = ||w||^2 - 2*dot ; running argmin (ascending code => first-min tie-break)
        #pragma unroll
        for (int j4 = 0; j4 < 4; ++j4) {
            float4 wq = *reinterpret_cast<const float4*>(wsqst + cbase + ty * 16 + j4 * 4);
            const float wqa[4] = {wq.x, wq.y, wq.z, wq.w};
            #pragma unroll
            for (int jj = 0; jj < 4; ++jj) {
                int j = j4 * 4 + jj;
                int code = cbase + ty * 16 + j;
                #pragma unroll
                for (int i = 0; i < 4; ++i) {
                    float dist = wqa[jj] - 2.0f * acc[i][j];
                    if (dist < best[i]) { best[i] = dist; bkst[i] = code; }
                }
            }
        }
    }

    // ---- cross-group argmin reduction
    #pragma unroll
    for (int i = 0; i < 4; ++i) {
        red_d[(tx * 4 + i) * 16 + ty] = best[i];
        red_k[(tx * 4 + i) * 16 + ty] = bkst[i];
    }
    __syncthreads();
    if (t < 64) {
        int tok = t;
        float bd = red_d[tok * 16];
        int   bk = red_k[tok * 16];
        #pragma unroll
        for (int g = 1; g < 16; ++g) {
            float dg = red_d[tok * 16 + g];
            int   kg = red_k[tok * 16 + g];
            if (dg < bd || (dg == bd && kg < bk)) { bd = dg; bk = kg; }
        }
        kbest[tok] = bk;
        codes_out[(size_t)(tok0 + tok) * QST + stage] = (float)bk;
        atomicAdd(cc_acc + bk, 1.0f);
    }
    __syncthreads();

    // ---- update: rm_acc[k] += r_old ; r_new = r_old - w[k]
    #pragma unroll
    for (int it = 0; it < 32; ++it) {
        int idx = it * 256 + t;        // 64 tok * 128 d
        int tok = idx >> 7;
        int d   = idx & 127;
        int k   = kbest[tok];
        float rold = A[a_idx(d, tok)];
        float wv   = wst[(size_t)k * DIMS + d];
        atomicAdd(rm_acc + (size_t)k * DIMS + d, rold);
        rout[(size_t)(tok0 + tok) * DIMS + d] = rold - wv;
    }
}

// ||w||^2 per code row, all stages at once. One wave per row.
__global__ void rvq_wsq(const float* __restrict__ w, float* __restrict__ wsq) {
    int row  = blockIdx.x * 4 + (threadIdx.x >> 6);
    int lane = threadIdx.x & 63;
    const float* wr = w + (size_t)row * DIMS;
    float a = wr[lane];
    float b = wr[lane + 64];
    float v = a * a + b * b;
    #pragma unroll
    for (int off = 32; off > 0; off >>= 1) v += __shfl_down(v, off, 64);
    if (lane == 0) wsq[row] = v;
}

// quantized = x - r (in place over the r buffer) + commitment-loss partial sums
__global__ void rvq_quant_loss(const float* __restrict__ x,
                               float* __restrict__ rq,
                               float* __restrict__ loss_acc) {
    __shared__ float ws[4];
    int tid = blockIdx.x * 256 + threadIdx.x;
    float lsum = 0.0f;
    #pragma unroll
    for (int rep = 0; rep < 4; ++rep) {
        size_t q = (size_t)tid + (size_t)rep * 262144;   // 1,048,576 float4s total
        float4 rv = *reinterpret_cast<float4*>(rq + q * 4);
        float4 xv = *reinterpret_cast<const float4*>(x + q * 4);
        lsum += rv.x*rv.x + rv.y*rv.y + rv.z*rv.z + rv.w*rv.w;
        float4 o;
        o.x = xv.x - rv.x; o.y = xv.y - rv.y; o.z = xv.z - rv.z; o.w = xv.w - rv.w;
        *reinterpret_cast<float4*>(rq + q * 4) = o;
    }
    #pragma unroll
    for (int off = 32; off > 0; off >>= 1) lsum += __shfl_down(lsum, off, 64);
    if ((threadIdx.x & 63) == 0) ws[threadIdx.x >> 6] = lsum;
    __syncthreads();
    if (threadIdx.x == 0) atomicAdd(loss_acc, ws[0] + ws[1] + ws[2] + ws[3]);
}

// finalize code_count (and write loss scalar)
__global__ void rvq_fin_cc(const float* __restrict__ cc_in,
                           float* __restrict__ cc_io,
                           const float* __restrict__ loss_acc,
                           float* __restrict__ loss_out) {
    int i = blockIdx.x * 256 + threadIdx.x;   // 8192
    float accv = cc_io[i];
    cc_io[i] = cc_in[i] * 0.99f + (accv / 32768.0f) * 0.01f;
    if (i == 0) loss_out[0] = loss_acc[0] / (float)(NTOK * DIMS);
}

// finalize running_mean + weight (needs finalized cc)
__global__ void rvq_fin_rmw(const float* __restrict__ rm_in,
                            float* __restrict__ rm_io,
                            float* __restrict__ w_out,
                            const float* __restrict__ cc_fin) {
    int i = blockIdx.x * 256 + threadIdx.x;   // 1,048,576
    float accv = rm_io[i];
    float nrm = rm_in[i] * 0.99f + (accv / 32768.0f) * 0.01f;
    rm_io[i] = nrm;
    w_out[i] = nrm / (1e-10f + cc_fin[i >> 7]);
}

extern "C" void kernel_launch(void* const* d_in, const int* in_sizes, int n_in,
                              void* d_out, int out_size, void* d_ws, size_t ws_size,
                              hipStream_t stream) {
    const float* x   = (const float*)d_in[0];
    const float* w   = (const float*)d_in[1];
    const float* rm  = (const float*)d_in[2];
    const float* cc  = (const float*)d_in[3];
    float* out   = (float*)d_out;
    float* quant = out;                    // doubles as the residual buffer
    float* codes = out + OFF_CODES;
    float* loss  = out + OFF_LOSS;
    float* wout  = out + OFF_W;
    float* rmout = out + OFF_RM;
    float* ccout = out + OFF_CC;
    float* lacc  = (float*)d_ws;           // [0]: loss accumulator
    float* wsq   = (float*)d_ws + 4;       // 16B-aligned, Q*K floats

    // zero accumulators (rm + cc regions are contiguous) and loss slot
    hipMemsetAsync(rmout, 0, (size_t)(SZ_W + QST * KC) * sizeof(float), stream);
    hipMemsetAsync(d_ws, 0, 16, stream);

    rvq_wsq<<<QST * KC / 4, 256, 0, stream>>>(w, wsq);

    for (int s = 0; s < QST; ++s) {
        const float* rin = (s == 0) ? x : quant;
        rvq_stage<<<NTOK / 64, 256, 0, stream>>>(
            rin, quant,
            w + (size_t)s * KC * DIMS,
            wsq + (size_t)s * KC,
            codes,
            rmout + (size_t)s * KC * DIMS,
            ccout + (size_t)s * KC,
            s);
    }

    rvq_quant_loss<<<1024, 256, 0, stream>>>(x, quant, lacc);
    rvq_fin_cc<<<QST * KC / 256, 256, 0, stream>>>(cc, ccout, lacc, loss);
    rvq_fin_rmw<<<SZ_W / 256, 256, 0, stream>>>(rm, rmout, wout, ccout);
}